// Round 15
// baseline (537.292 us; speedup 1.0000x reference)
//
#include <hip/hip_runtime.h>
#include <hip/hip_bf16.h>
#include <math.h>
#include <float.h>
#include <limits.h>

#define N_TOT   16384
#define DIM     256
#define KCB     8192
#define LSEQ    2048
#define TAU_A   1.8e-5f
#define W_CERT  1.7e-5f

typedef unsigned short u16;
typedef unsigned int   u32;
typedef unsigned long long u64;
typedef __attribute__((ext_vector_type(8))) short bf16x8;
typedef __attribute__((ext_vector_type(4))) float f32x4;

// ws layout (bytes)
#define WS_ZT_HI 0u
#define WS_ZT_LO 8388608u
#define WS_E_HI  16777216u
#define WS_E_LO  20971520u
#define WS_SZ    25165824u
#define WS_IDX   25231360u
#define WS_I2G   25296896u
#define WS_LIST2 25362432u
#define WS_CNT   25427968u
#define WS_PART  25428992u
#define WS_PA1   25430016u
#define WS_PA2   25692160u
#define WS_PA3   25954304u
#define WS_PI1   26216448u
#define WS_PI2   26478592u
#define WS_LISTR 26740736u
#define WS_RB    26806272u

__device__ __forceinline__ u16 f2bf_bits(float x) {
  __hip_bfloat16 h = __float2bfloat16(x);
  return *reinterpret_cast<u16*>(&h);
}
__device__ __forceinline__ float bfbits2f(u16 b) {
  __hip_bfloat16 h = *reinterpret_cast<__hip_bfloat16*>(&b);
  return __bfloat162float(h);
}

__device__ __forceinline__ void gl_lds16(const void* g, void* l) {
  __builtin_amdgcn_global_load_lds(
      (const __attribute__((address_space(1))) u32*)g,
      (__attribute__((address_space(3))) u32*)l, 16, 0, 0);
}

// merge two sorted (desc, idx-asc-on-tie) triples; slot3 value-only
__device__ __forceinline__ void mrg(float& a1, int& i1, float& a2, int& i2, float& a3,
                                    float b1, int j1, float b2, int j2, float b3) {
  bool bfirst = (b1 > a1) || (b1 == a1 && j1 < i1);
  float c1 = bfirst ? b1 : a1;
  int   k1 = bfirst ? j1 : i1;
  float wh2 = bfirst ? b2 : a2, wh3 = bfirst ? b3 : a3;
  int   wk2 = bfirst ? j2 : i2;
  float lh1 = bfirst ? a1 : b1, lh2 = bfirst ? a2 : b2;
  int   lk1 = bfirst ? i1 : j1;
  bool l2 = (lh1 > wh2) || (lh1 == wh2 && lk1 < wk2);
  float c2, c3; int k2;
  if (l2) { c2 = lh1; k2 = lk1; c3 = fmaxf(wh2, lh2); }
  else    { c2 = wh2; k2 = wk2; c3 = fmaxf(wh3, lh1); }
  a1 = c1; i1 = k1; a2 = c2; i2 = k2; a3 = c3;
}

// ---------- fused: split z -> bf16 hi/lo AND np-replica row norms ----------
__global__ __launch_bounds__(256) void k_prep(const float* __restrict__ z,
                                              u16* __restrict__ zhi,
                                              u16* __restrict__ zlo,
                                              float* __restrict__ sz) {
  int g = blockIdx.x * 256 + threadIdx.x;   // 32768 = 16384 rows x 2 halves
  int n = g >> 1, half = g & 1;
  int b = n >> 11, l = n & (LSEQ - 1);
  const float* zp = z + (size_t)b * DIM * LSEQ + l;
  const int d0 = half * 128;
  u16* ph = zhi + (size_t)n * DIM + d0;
  u16* pl = zlo + (size_t)n * DIM + d0;
  float r[8];
  u32 hw[8], lw[8];
  #pragma unroll
  for (int i = 0; i < 128; i += 8) {
    #pragma unroll
    for (int j = 0; j < 8; ++j) {
      int dd = i + j;
      float v = zp[(size_t)(d0 + dd) * LSEQ];
      float sq = __fmul_rn(v, v);
      r[j] = (i == 0) ? sq : __fadd_rn(r[j], sq);
      u16 hb = f2bf_bits(v);
      u16 lb = f2bf_bits(v - bfbits2f(hb));
      int wi = (dd >> 1) & 7;
      if (dd & 1) { hw[wi] |= (u32)hb << 16; lw[wi] |= (u32)lb << 16; }
      else        { hw[wi]  = hb;            lw[wi]  = lb; }
    }
    if (i & 8) {
      int gb = i - 8;
      *(uint4*)(ph + gb)     = make_uint4(hw[0], hw[1], hw[2], hw[3]);
      *(uint4*)(ph + gb + 8) = make_uint4(hw[4], hw[5], hw[6], hw[7]);
      *(uint4*)(pl + gb)     = make_uint4(lw[0], lw[1], lw[2], lw[3]);
      *(uint4*)(pl + gb + 8) = make_uint4(lw[4], lw[5], lw[6], lw[7]);
    }
  }
  float hsum = __fadd_rn(__fadd_rn(__fadd_rn(r[0], r[1]), __fadd_rn(r[2], r[3])),
                         __fadd_rn(__fadd_rn(r[4], r[5]), __fadd_rn(r[6], r[7])));
  float other = __shfl_xor(hsum, 1, 64);
  if (half == 0) sz[n] = __fadd_rn(hsum, other);
}

// ---------- split emb [k][d] -> e_hi/e_lo bf16 (+ counters zero) ----------
__global__ __launch_bounds__(256) void k_split_e(const float* __restrict__ emb,
                                                 u16* __restrict__ ehi,
                                                 u16* __restrict__ elo,
                                                 int* __restrict__ cnt) {
  if (blockIdx.x == 0 && threadIdx.x == 0) { cnt[0] = 0; cnt[1] = 0; }
  int g = blockIdx.x * 256 + threadIdx.x;   // 2048 blocks, 4 floats each
  float4 v = ((const float4*)emb)[g];
  u16 h0 = f2bf_bits(v.x), h1 = f2bf_bits(v.y), h2 = f2bf_bits(v.z), h3 = f2bf_bits(v.w);
  u16 l0 = f2bf_bits(v.x - bfbits2f(h0));
  u16 l1 = f2bf_bits(v.y - bfbits2f(h1));
  u16 l2 = f2bf_bits(v.z - bfbits2f(h2));
  u16 l3 = f2bf_bits(v.w - bfbits2f(h3));
  ((uint2*)ehi)[g] = make_uint2((u32)h0 | ((u32)h1 << 16), (u32)h2 | ((u32)h3 << 16));
  ((uint2*)elo)[g] = make_uint2((u32)l0 | ((u32)l1 << 16), (u32)l2 | ((u32)l3 << 16));
}

// ---------- MFMA top-3 phase-1: z-in-reg, 32-code e-tiles, 2 blocks/CU ----------
// grid 512 = 128 row-blocks x 4 code-quarters (2048 codes each); 512 threads
// (8 waves, 4 wr x 2 wc). LDS = 2 x 32KB e dbuf only -> 2 blocks/CU (4 w/SIMD).
// 64 tiles of 32 codes, full K=256 per tile; per-code accumulation order
// identical to rounds 12-14 => bit-identical dots. Quarters merged in k_merge.
__global__ __launch_bounds__(512, 4) void k_mfma(const u16* __restrict__ zhi_g,
                                                 const u16* __restrict__ zlo_g,
                                                 const u16* __restrict__ ehi_g,
                                                 const u16* __restrict__ elo_g,
                                                 float* __restrict__ pa1,
                                                 float* __restrict__ pa2,
                                                 float* __restrict__ pa3,
                                                 int* __restrict__ pi1,
                                                 int* __restrict__ pi2) {
  extern __shared__ char smem[];
  const int tid = threadIdx.x;
  const int lane = tid & 63, w = tid >> 6;
  const int wr = w >> 1, wc = w & 1;          // 4 row-waves x 2 col-waves
  const int bid = blockIdx.x;
  const int quarter = bid & 3;
  const int rb = (bid >> 2) * 128;
  const size_t zrow0 = (size_t)rb * 512;
  const size_t ecol0 = (size_t)quarter * 2048 * 512;
  const int srcoff = ((lane >> 3) << 9) + ((((lane & 7) ^ ((lane >> 3) & 7))) << 4);
  const int sarr = w & 1;                     // staging role: 0=hi, 1=lo
  const int sgrp = w >> 1;                    // 0..3

  // z fragments -> registers (32 x bf16x8 per thread)
  bf16x8 zfh[2][8], zfl[2][8];
  {
    const char* zh = (const char*)zhi_g + zrow0;
    const char* zl = (const char*)zlo_g + zrow0;
    #pragma unroll
    for (int rt = 0; rt < 2; ++rt) {
      int rowb = (wr * 32 + rt * 16 + (lane & 15)) * 512 + ((lane >> 4) << 4);
      #pragma unroll
      for (int ks = 0; ks < 8; ++ks) {
        zfh[rt][ks] = *(const bf16x8*)(zh + rowb + ks * 64);
        zfl[rt][ks] = *(const bf16x8*)(zl + rowb + ks * 64);
      }
    }
  }

  // e staging: tile T (32 codes x 256 d, hi+lo = 32KB) into dbuf half (T&1)
  // LDS layout per array side: [dq 0..3][code 0..31][128B chunk^((code&7))]
  #define STAGE_E(T) {                                                      \
    const char* esrc_ = ((sarr == 0) ? (const char*)ehi_g                   \
                                     : (const char*)elo_g) + ecol0          \
                        + (size_t)(T) * 16384;                              \
    char* ebuf_ = smem + (((T) & 1) << 15) + sarr * 16384;                  \
    _Pragma("unroll")                                                       \
    for (int dq_ = 0; dq_ < 4; ++dq_) {                                     \
      gl_lds16(esrc_ + sgrp * 4096 + dq_ * 128 + srcoff,                    \
               ebuf_ + dq_ * 4096 + sgrp * 1024);                           \
    }                                                                       \
  }

  STAGE_E(0);

  f32x4 acc[2];
  #pragma unroll
  for (int rc = 0; rc < 2; ++rc) acc[rc] = (f32x4){0.f, 0.f, 0.f, 0.f};

  float a1[2], a2[2], a3[2]; int i1[2], i2[2];
  #pragma unroll
  for (int rc = 0; rc < 2; ++rc) {
    a1[rc] = -FLT_MAX; a2[rc] = -FLT_MAX; a3[rc] = -FLT_MAX; i1[rc] = 0; i2[rc] = 0;
  }

  const int cbyte = (wc * 16 + (lane & 15)) * 128;

  __syncthreads();

  for (int t = 0; t < 64; ++t) {
    if (t + 1 < 64) STAGE_E(t + 1);
    const char* bb = smem + ((t & 1) << 15);
    #pragma unroll
    for (int ks = 0; ks < 8; ++ks) {
      const int dq = ks >> 1, kc = ks & 1;
      const char* beh = bb + dq * 4096;
      const char* bel = bb + 16384 + dq * 4096;
      int coff = ((kc * 4 + (lane >> 4)) ^ (lane & 7)) << 4;
      bf16x8 ah = *(const bf16x8*)(beh + cbyte + coff);
      bf16x8 al = *(const bf16x8*)(bel + cbyte + coff);
      #pragma unroll
      for (int rc = 0; rc < 2; ++rc) {
        acc[rc] = __builtin_amdgcn_mfma_f32_16x16x32_bf16(ah, zfh[rc][ks], acc[rc], 0, 0, 0);
        acc[rc] = __builtin_amdgcn_mfma_f32_16x16x32_bf16(ah, zfl[rc][ks], acc[rc], 0, 0, 0);
        acc[rc] = __builtin_amdgcn_mfma_f32_16x16x32_bf16(al, zfh[rc][ks], acc[rc], 0, 0, 0);
      }
    }
    {   // per-tile branch-free top-3 update (codes ascending)
      int cbase = quarter * 2048 + t * 32 + wc * 16 + (lane >> 4) * 4;
      #pragma unroll
      for (int rc = 0; rc < 2; ++rc) {
        #pragma unroll
        for (int r = 0; r < 4; ++r) {
          float v = acc[rc][r];
          int code = cbase + r;
          bool gt1 = v > a1[rc];
          bool gt2 = v > a2[rc];
          float n1 = fmaxf(a1[rc], v);
          float n2 = __builtin_amdgcn_fmed3f(a1[rc], a2[rc], v);
          float n3 = fmaxf(a3[rc], fminf(a2[rc], v));
          int ni1 = gt1 ? code : i1[rc];
          int ni2 = gt1 ? i1[rc] : (gt2 ? code : i2[rc]);
          a1[rc] = n1; a2[rc] = n2; a3[rc] = n3; i1[rc] = ni1; i2[rc] = ni2;
        }
        acc[rc] = (f32x4){0.f, 0.f, 0.f, 0.f};
      }
    }
    __syncthreads();
  }
  #undef STAGE_E

  // merge lane-groups (lane^16, lane^32) holding the same z-row
  #pragma unroll
  for (int rc = 0; rc < 2; ++rc) {
    #pragma unroll
    for (int off = 16; off < 64; off <<= 1) {
      float b1 = __shfl_xor(a1[rc], off, 64);
      float b2 = __shfl_xor(a2[rc], off, 64);
      float b3 = __shfl_xor(a3[rc], off, 64);
      int   j1 = __shfl_xor(i1[rc], off, 64);
      int   j2 = __shfl_xor(i2[rc], off, 64);
      mrg(a1[rc], i1[rc], a2[rc], i2[rc], a3[rc], b1, j1, b2, j2, b3);
    }
  }
  // cross-wave (wc) merge via LDS
  float* sa1 = (float*)smem;            // [2][128] each
  float* sa2 = sa1 + 256;
  float* sa3 = sa2 + 256;
  int*   si1 = (int*)(sa3 + 256);
  int*   si2 = si1 + 256;
  if ((lane >> 4) == 0) {
    #pragma unroll
    for (int rc = 0; rc < 2; ++rc) {
      int rl = wr * 32 + rc * 16 + lane;
      sa1[wc * 128 + rl] = a1[rc];
      sa2[wc * 128 + rl] = a2[rc];
      sa3[wc * 128 + rl] = a3[rc];
      si1[wc * 128 + rl] = i1[rc];
      si2[wc * 128 + rl] = i2[rc];
    }
  }
  __syncthreads();
  if (tid < 128) {
    float g1 = sa1[tid], g2 = sa2[tid], g3 = sa3[tid];
    int gi1 = si1[tid], gi2 = si2[tid];
    mrg(g1, gi1, g2, gi2, g3,
        sa1[128 + tid], si1[128 + tid],
        sa2[128 + tid], si2[128 + tid], sa3[128 + tid]);
    int n = rb + tid;
    pa1[quarter * N_TOT + n] = g1;
    pa2[quarter * N_TOT + n] = g2;
    pa3[quarter * N_TOT + n] = g3;
    pi1[quarter * N_TOT + n] = gi1;
    pi2[quarter * N_TOT + n] = gi2;
  }
}

// ---------- merge 4 quarters; emit idx, i2, and confirm/rescan lists ----------
__global__ __launch_bounds__(256) void k_merge(const float* __restrict__ pa1,
                                               const float* __restrict__ pa2,
                                               const float* __restrict__ pa3,
                                               const int* __restrict__ pi1,
                                               const int* __restrict__ pi2,
                                               int* __restrict__ idx,
                                               int* __restrict__ i2g,
                                               int* __restrict__ list2,
                                               int* __restrict__ listR,
                                               int* __restrict__ cnt,
                                               u64* __restrict__ rowbest) {
  int n = blockIdx.x * 256 + threadIdx.x;
  float g1 = pa1[n], g2 = pa2[n], g3 = pa3[n];
  int gi1 = pi1[n], gi2 = pi2[n];
  #pragma unroll
  for (int q = 1; q < 4; ++q) {
    mrg(g1, gi1, g2, gi2, g3,
        pa1[q * N_TOT + n], pi1[q * N_TOT + n],
        pa2[q * N_TOT + n], pi2[q * N_TOT + n], pa3[q * N_TOT + n]);
  }
  idx[n] = gi1;
  i2g[n] = gi2;
  if (g1 - g2 < TAU_A) {
    if (g1 - g3 >= W_CERT) { int p = atomicAdd(&cnt[0], 1); list2[p] = n; }
    else {
      int p = atomicAdd(&cnt[1], 1); listR[p] = n;
      rowbest[n] = 0xFFFFFFFFFFFFFFFFull;
    }
  }
}

// ---------- fused fixup: blocks 0..255 confirm-2, blocks 256..1279 rescan ----------
__global__ __launch_bounds__(256) void k_fix(const float* __restrict__ z,
                                             const float* __restrict__ emb,
                                             const float* __restrict__ szt,
                                             int* __restrict__ idx,
                                             const int* __restrict__ i2g,
                                             const int* __restrict__ list2,
                                             const int* __restrict__ listR,
                                             const int* __restrict__ cnt,
                                             u64* __restrict__ rowbest) {
  __shared__ float zrow[DIM];
  const int tid = threadIdx.x;
  const int lane = tid & 63, w = tid >> 6;
  if (blockIdx.x < 256) {
    // wave-parallel exact D over {i1, i2}
    const int nc = cnt[0];
    for (int q = blockIdx.x * 4 + w; q < nc; q += 1024) {
      int n = list2[q];
      int b = n >> 11, l = n & (LSEQ - 1);
      int c0 = idx[n], c1 = i2g[n];
      const float* zp = z + (size_t)b * DIM * LSEQ + l;
      float4 e0 = ((const float4*)emb)[(size_t)c0 * 64 + lane];
      float4 e1 = ((const float4*)emb)[(size_t)c1 * 64 + lane];
      float z0 = zp[(size_t)(4 * lane + 0) * LSEQ];
      float z1 = zp[(size_t)(4 * lane + 1) * LSEQ];
      float z2 = zp[(size_t)(4 * lane + 2) * LSEQ];
      float z3 = zp[(size_t)(4 * lane + 3) * LSEQ];
      double d0 = 0.0, d1 = 0.0;
      d0 = fma((double)e0.x, (double)z0, d0); d1 = fma((double)e1.x, (double)z0, d1);
      d0 = fma((double)e0.y, (double)z1, d0); d1 = fma((double)e1.y, (double)z1, d1);
      d0 = fma((double)e0.z, (double)z2, d0); d1 = fma((double)e1.z, (double)z2, d1);
      d0 = fma((double)e0.w, (double)z3, d0); d1 = fma((double)e1.w, (double)z3, d1);
      #pragma unroll
      for (int off = 32; off; off >>= 1) {
        d0 += __shfl_xor(d0, off, 64);
        d1 += __shfl_xor(d1, off, 64);
      }
      if (lane == 0) {
        float szv = szt[n];
        float D0 = __fsub_rn(szv, __fmul_rn(2.f, (float)d0));
        float D1 = __fsub_rn(szv, __fmul_rn(2.f, (float)d1));
        idx[n] = (D1 < D0 || (D1 == D0 && c1 < c0)) ? c1 : c0;
      }
    }
  } else {
    // rare-row rescan: wave-per-code-chunk, lane-parallel d, ILP-4 code batch
    const int nr = cnt[1];
    const int nitems = nr * 8;
    for (int item = blockIdx.x - 256; item < nitems; item += 1024) {
      int q = item >> 3, ck = item & 7;
      int n = listR[q];
      int b = n >> 11, l = n & (LSEQ - 1);
      zrow[tid] = z[(size_t)b * DIM * LSEQ + (size_t)tid * LSEQ + l];
      __syncthreads();
      float szv = szt[n];
      float zr0 = zrow[lane * 4 + 0], zr1 = zrow[lane * 4 + 1];
      float zr2 = zrow[lane * 4 + 2], zr3 = zrow[lane * 4 + 3];
      float bD = FLT_MAX; int bK = INT_MAX;
      int code0 = ck * 1024 + w * 256;
      for (int c4 = 0; c4 < 64; ++c4) {
        int codeb = code0 + c4 * 4;
        double dt[4];
        #pragma unroll
        for (int u = 0; u < 4; ++u) {
          float4 e4 = ((const float4*)emb)[(size_t)(codeb + u) * 64 + lane];
          double dot = 0.0;
          dot = fma((double)e4.x, (double)zr0, dot);
          dot = fma((double)e4.y, (double)zr1, dot);
          dot = fma((double)e4.z, (double)zr2, dot);
          dot = fma((double)e4.w, (double)zr3, dot);
          dt[u] = dot;
        }
        #pragma unroll
        for (int off = 32; off; off >>= 1) {
          #pragma unroll
          for (int u = 0; u < 4; ++u) dt[u] += __shfl_xor(dt[u], off, 64);
        }
        #pragma unroll
        for (int u = 0; u < 4; ++u) {
          int code = codeb + u;
          float D = __fsub_rn(szv, __fmul_rn(2.f, (float)dt[u]));
          if (D < bD || (D == bD && code < bK)) { bD = D; bK = code; }
        }
      }
      if (lane == 0) {
        u64 key = ((u64)__float_as_uint(bD) << 32) | (u32)bK;
        atomicMin(rowbest + n, key);
      }
      __syncthreads();
    }
  }
}

// ---------- resolve rescan winners into idx ----------
__global__ __launch_bounds__(256) void k_resolve(int* __restrict__ idx,
                                                 const u64* __restrict__ rowbest,
                                                 const int* __restrict__ listR,
                                                 const int* __restrict__ cnt) {
  const int nr = cnt[1];
  for (int q = blockIdx.x * 256 + threadIdx.x; q < nr; q += gridDim.x * 256) {
    int n = listR[q];
    u64 rbv = rowbest[n];
    if (rbv != 0xFFFFFFFFFFFFFFFFull) idx[n] = (int)(rbv & 0xFFFFFFFFu);
  }
}

// ---------- gather + loss partials ----------
__global__ __launch_bounds__(256) void k_gather(const float* __restrict__ z,
                                                const float* __restrict__ emb,
                                                const int* __restrict__ idx,
                                                float* __restrict__ zq_out,
                                                float* __restrict__ idxf_out,
                                                float* __restrict__ partial) {
  __shared__ int il[64];
  __shared__ float red[4];
  const int tid = threadIdx.x;
  const int n0 = blockIdx.x * 64;
  const int b = n0 >> 11, l0 = n0 & (LSEQ - 1);
  if (tid < 64) {
    int v = idx[n0 + tid];
    il[tid] = v;
    idxf_out[n0 + tid] = (float)v;
  }
  __syncthreads();
  const int dgrp = tid >> 6;
  const int lo   = tid & 63;
  const size_t zb = (size_t)b * DIM * LSEQ + l0 + lo;
  const int myidx = il[lo];
  float acc = 0.f;
  #pragma unroll 4
  for (int dd = 0; dd < 64; ++dd) {
    int d = dgrp + dd * 4;
    float e  = emb[(size_t)myidx * DIM + d];
    float zv = z[zb + (size_t)d * LSEQ];
    zq_out[zb + (size_t)d * LSEQ] = e;
    float df = e - zv;
    acc = fmaf(df, df, acc);
  }
  #pragma unroll
  for (int off = 1; off < 64; off <<= 1) acc += __shfl_xor(acc, off, 64);
  if ((tid & 63) == 0) red[tid >> 6] = acc;
  __syncthreads();
  if (tid == 0) partial[blockIdx.x] = red[0] + red[1] + red[2] + red[3];
}

__global__ __launch_bounds__(256) void k_loss(const float* __restrict__ partial,
                                              float* __restrict__ out_loss) {
  const int tid = threadIdx.x;
  double a = (double)partial[tid];
  #pragma unroll
  for (int off = 1; off < 64; off <<= 1) a += __shfl_xor(a, off, 64);
  __shared__ double r[4];
  if ((tid & 63) == 0) r[tid >> 6] = a;
  __syncthreads();
  if (tid == 0) {
    double s = r[0] + r[1] + r[2] + r[3];
    out_loss[0] = (float)(1.25 * s / (double)((size_t)N_TOT * DIM));
  }
}

extern "C" void kernel_launch(void* const* d_in, const int* in_sizes, int n_in,
                              void* d_out, int out_size, void* d_ws, size_t ws_size,
                              hipStream_t stream) {
  const float* z   = (const float*)d_in[0];
  const float* emb = (const float*)d_in[1];
  float* out = (float*)d_out;
  char* ws = (char*)d_ws;

  u16*   zhi  = (u16*)(ws + WS_ZT_HI);
  u16*   zlo  = (u16*)(ws + WS_ZT_LO);
  u16*   ehi  = (u16*)(ws + WS_E_HI);
  u16*   elo  = (u16*)(ws + WS_E_LO);
  float* sz   = (float*)(ws + WS_SZ);
  int*   idx  = (int*)(ws + WS_IDX);
  int*   i2g  = (int*)(ws + WS_I2G);
  int*   list2= (int*)(ws + WS_LIST2);
  int*   cnt  = (int*)(ws + WS_CNT);
  float* part = (float*)(ws + WS_PART);
  float* pa1  = (float*)(ws + WS_PA1);
  float* pa2  = (float*)(ws + WS_PA2);
  float* pa3  = (float*)(ws + WS_PA3);
  int*   pi1  = (int*)(ws + WS_PI1);
  int*   pi2  = (int*)(ws + WS_PI2);
  int*   listR= (int*)(ws + WS_LISTR);
  u64*   rb   = (u64*)(ws + WS_RB);

  float* zq_out   = out;
  float* loss_out = out + (size_t)N_TOT * DIM;
  float* idxf_out = out + (size_t)N_TOT * DIM + 1;

  k_prep   <<<128,  256, 0, stream>>>(z, zhi, zlo, sz);
  k_split_e<<<2048, 256, 0, stream>>>(emb, ehi, elo, cnt);
  k_mfma   <<<512,  512, 65536, stream>>>(zhi, zlo, ehi, elo, pa1, pa2, pa3, pi1, pi2);
  k_merge  <<<64,   256, 0, stream>>>(pa1, pa2, pa3, pi1, pi2, idx, i2g, list2, listR, cnt, rb);
  k_fix    <<<1280, 256, 0, stream>>>(z, emb, sz, idx, i2g, list2, listR, cnt, rb);
  k_resolve<<<8,    256, 0, stream>>>(idx, rb, listR, cnt);
  k_gather <<<256,  256, 0, stream>>>(z, emb, idx, zq_out, idxf_out, part);
  k_loss   <<<1,    256, 0, stream>>>(part, loss_out);
}

// Round 16
// 309.248 us; speedup vs baseline: 1.7374x; 1.7374x over previous
//
#include <hip/hip_runtime.h>
#include <hip/hip_bf16.h>
#include <math.h>
#include <float.h>
#include <limits.h>

#define N_TOT   16384
#define DIM     256
#define KCB     8192
#define LSEQ    2048
#define TAU_A   1.8e-5f
#define W_CERT  1.7e-5f

typedef unsigned short u16;
typedef unsigned int   u32;
typedef unsigned long long u64;
typedef __attribute__((ext_vector_type(8))) short bf16x8;
typedef __attribute__((ext_vector_type(4))) float f32x4;

// ws layout (bytes)
#define WS_ZT_HI 0u
#define WS_ZT_LO 8388608u
#define WS_E_HI  16777216u
#define WS_E_LO  20971520u
#define WS_SZ    25165824u
#define WS_IDX   25231360u
#define WS_I2G   25296896u
#define WS_LIST2 25362432u
#define WS_CNT   25427968u
#define WS_PART  25428992u
#define WS_PA1   25430016u
#define WS_PA2   25561088u
#define WS_PI1   25692160u
#define WS_PA3   25823232u
#define WS_PI2   25954304u
#define WS_LISTR 26085376u
#define WS_RB    26150912u

__device__ __forceinline__ u16 f2bf_bits(float x) {
  __hip_bfloat16 h = __float2bfloat16(x);
  return *reinterpret_cast<u16*>(&h);
}
__device__ __forceinline__ float bfbits2f(u16 b) {
  __hip_bfloat16 h = *reinterpret_cast<__hip_bfloat16*>(&b);
  return __bfloat162float(h);
}

__device__ __forceinline__ void gl_lds16(const void* g, void* l) {
  __builtin_amdgcn_global_load_lds(
      (const __attribute__((address_space(1))) u32*)g,
      (__attribute__((address_space(3))) u32*)l, 16, 0, 0);
}

// merge two sorted (desc, idx-asc-on-tie) triples; slot3 value-only
__device__ __forceinline__ void mrg(float& a1, int& i1, float& a2, int& i2, float& a3,
                                    float b1, int j1, float b2, int j2, float b3) {
  bool bfirst = (b1 > a1) || (b1 == a1 && j1 < i1);
  float c1 = bfirst ? b1 : a1;
  int   k1 = bfirst ? j1 : i1;
  float wh2 = bfirst ? b2 : a2, wh3 = bfirst ? b3 : a3;
  int   wk2 = bfirst ? j2 : i2;
  float lh1 = bfirst ? a1 : b1, lh2 = bfirst ? a2 : b2;
  int   lk1 = bfirst ? i1 : j1;
  bool l2 = (lh1 > wh2) || (lh1 == wh2 && lk1 < wk2);
  float c2, c3; int k2;
  if (l2) { c2 = lh1; k2 = lk1; c3 = fmaxf(wh2, lh2); }
  else    { c2 = wh2; k2 = wk2; c3 = fmaxf(wh3, lh1); }
  a1 = c1; i1 = k1; a2 = c2; i2 = k2; a3 = c3;
}

// ---------- fused: split z -> bf16 hi/lo AND np-replica row norms ----------
__global__ __launch_bounds__(256) void k_prep(const float* __restrict__ z,
                                              u16* __restrict__ zhi,
                                              u16* __restrict__ zlo,
                                              float* __restrict__ sz) {
  int g = blockIdx.x * 256 + threadIdx.x;   // 32768 = 16384 rows x 2 halves
  int n = g >> 1, half = g & 1;
  int b = n >> 11, l = n & (LSEQ - 1);
  const float* zp = z + (size_t)b * DIM * LSEQ + l;
  const int d0 = half * 128;
  u16* ph = zhi + (size_t)n * DIM + d0;
  u16* pl = zlo + (size_t)n * DIM + d0;
  float r[8];
  u32 hw[8], lw[8];
  #pragma unroll
  for (int i = 0; i < 128; i += 8) {
    #pragma unroll
    for (int j = 0; j < 8; ++j) {
      int dd = i + j;
      float v = zp[(size_t)(d0 + dd) * LSEQ];
      float sq = __fmul_rn(v, v);
      r[j] = (i == 0) ? sq : __fadd_rn(r[j], sq);
      u16 hb = f2bf_bits(v);
      u16 lb = f2bf_bits(v - bfbits2f(hb));
      int wi = (dd >> 1) & 7;
      if (dd & 1) { hw[wi] |= (u32)hb << 16; lw[wi] |= (u32)lb << 16; }
      else        { hw[wi]  = hb;            lw[wi]  = lb; }
    }
    if (i & 8) {
      int gb = i - 8;
      *(uint4*)(ph + gb)     = make_uint4(hw[0], hw[1], hw[2], hw[3]);
      *(uint4*)(ph + gb + 8) = make_uint4(hw[4], hw[5], hw[6], hw[7]);
      *(uint4*)(pl + gb)     = make_uint4(lw[0], lw[1], lw[2], lw[3]);
      *(uint4*)(pl + gb + 8) = make_uint4(lw[4], lw[5], lw[6], lw[7]);
    }
  }
  float hsum = __fadd_rn(__fadd_rn(__fadd_rn(r[0], r[1]), __fadd_rn(r[2], r[3])),
                         __fadd_rn(__fadd_rn(r[4], r[5]), __fadd_rn(r[6], r[7])));
  float other = __shfl_xor(hsum, 1, 64);
  if (half == 0) sz[n] = __fadd_rn(hsum, other);
}

// ---------- split emb [k][d] -> e_hi/e_lo bf16 (+ counters zero) ----------
__global__ __launch_bounds__(256) void k_split_e(const float* __restrict__ emb,
                                                 u16* __restrict__ ehi,
                                                 u16* __restrict__ elo,
                                                 int* __restrict__ cnt) {
  if (blockIdx.x == 0 && threadIdx.x == 0) { cnt[0] = 0; cnt[1] = 0; }
  int g = blockIdx.x * 256 + threadIdx.x;   // 2048 blocks, 4 floats each
  float4 v = ((const float4*)emb)[g];
  u16 h0 = f2bf_bits(v.x), h1 = f2bf_bits(v.y), h2 = f2bf_bits(v.z), h3 = f2bf_bits(v.w);
  u16 l0 = f2bf_bits(v.x - bfbits2f(h0));
  u16 l1 = f2bf_bits(v.y - bfbits2f(h1));
  u16 l2 = f2bf_bits(v.z - bfbits2f(h2));
  u16 l3 = f2bf_bits(v.w - bfbits2f(h3));
  ((uint2*)ehi)[g] = make_uint2((u32)h0 | ((u32)h1 << 16), (u32)h2 | ((u32)h3 << 16));
  ((uint2*)elo)[g] = make_uint2((u32)l0 | ((u32)l1 << 16), (u32)l2 | ((u32)l3 << 16));
}

// ---------- MFMA top-3 phase-1 (round-14 validated: z-in-reg, e-only LDS) ----------
__global__ __launch_bounds__(512) void k_mfma(const u16* __restrict__ zhi_g,
                                              const u16* __restrict__ zlo_g,
                                              const u16* __restrict__ ehi_g,
                                              const u16* __restrict__ elo_g,
                                              float* __restrict__ pa1,
                                              float* __restrict__ pa2,
                                              float* __restrict__ pa3,
                                              int* __restrict__ pi1,
                                              int* __restrict__ pi2) {
  extern __shared__ char smem[];
  const int tid = threadIdx.x;
  const int lane = tid & 63, w = tid >> 6;
  const int wr = w >> 1, wc = w & 1;          // 4 row-waves x 2 col-waves
  const int bid = blockIdx.x;
  const int half = bid & 1;
  const int rb = (bid >> 1) * 128;
  const size_t zrow0 = (size_t)rb * 512;
  const size_t ecol0 = (size_t)half * 4096 * 512;
  const int srcoff = ((lane >> 3) << 9) + ((((lane & 7) ^ ((lane >> 3) & 7))) << 4);
  const int sarr = w & 1;                     // staging role: 0=hi, 1=lo
  const int sgrp = w >> 1;                    // 0..3

  // z fragments -> registers (32 x bf16x8 per thread)
  bf16x8 zfh[2][8], zfl[2][8];
  {
    const char* zh = (const char*)zhi_g + zrow0;
    const char* zl = (const char*)zlo_g + zrow0;
    #pragma unroll
    for (int rt = 0; rt < 2; ++rt) {
      int rowb = (wr * 32 + rt * 16 + (lane & 15)) * 512 + ((lane >> 4) << 4);
      #pragma unroll
      for (int ks = 0; ks < 8; ++ks) {
        zfh[rt][ks] = *(const bf16x8*)(zh + rowb + ks * 64);
        zfl[rt][ks] = *(const bf16x8*)(zl + rowb + ks * 64);
      }
    }
  }

  // e staging: tile T (64 codes x 256 d, hi+lo = 64KB) into dbuf half (T&1)
  #define STAGE_E(T) {                                                      \
    const char* esrc_ = ((sarr == 0) ? (const char*)ehi_g                   \
                                     : (const char*)elo_g) + ecol0          \
                        + (size_t)(T) * 32768;                              \
    char* ebuf_ = smem + (((T) & 1) << 16) + sarr * 32768;                  \
    _Pragma("unroll")                                                       \
    for (int dq_ = 0; dq_ < 4; ++dq_) {                                     \
      _Pragma("unroll")                                                     \
      for (int j_ = 0; j_ < 2; ++j_) {                                      \
        int c_ = sgrp * 2 + j_;                                             \
        gl_lds16(esrc_ + c_ * 4096 + dq_ * 128 + srcoff,                    \
                 ebuf_ + dq_ * 8192 + c_ * 1024);                           \
      }                                                                     \
    }                                                                       \
  }

  STAGE_E(0);

  f32x4 acc[2][2];
  #pragma unroll
  for (int rc = 0; rc < 2; ++rc)
    #pragma unroll
    for (int cc = 0; cc < 2; ++cc) acc[rc][cc] = (f32x4){0.f, 0.f, 0.f, 0.f};

  float a1[2], a2[2], a3[2]; int i1[2], i2[2];
  #pragma unroll
  for (int rc = 0; rc < 2; ++rc) {
    a1[rc] = -FLT_MAX; a2[rc] = -FLT_MAX; a3[rc] = -FLT_MAX; i1[rc] = 0; i2[rc] = 0;
  }

  int cbyte[2];
  #pragma unroll
  for (int cc = 0; cc < 2; ++cc) cbyte[cc] = (wc * 32 + cc * 16 + (lane & 15)) * 128;

  __syncthreads();

  for (int t = 0; t < 64; ++t) {
    if (t + 1 < 64) STAGE_E(t + 1);
    const char* bb = smem + ((t & 1) << 16);
    #pragma unroll
    for (int ks = 0; ks < 8; ++ks) {
      const int dq = ks >> 1, kc = ks & 1;
      const char* beh = bb + dq * 8192;
      const char* bel = bb + 32768 + dq * 8192;
      int coff = ((kc * 4 + (lane >> 4)) ^ (lane & 7)) << 4;
      bf16x8 ah[2], al[2];
      #pragma unroll
      for (int cc = 0; cc < 2; ++cc) {
        ah[cc] = *(const bf16x8*)(beh + cbyte[cc] + coff);
        al[cc] = *(const bf16x8*)(bel + cbyte[cc] + coff);
      }
      #pragma unroll
      for (int rc = 0; rc < 2; ++rc)
        #pragma unroll
        for (int cc = 0; cc < 2; ++cc) {
          acc[rc][cc] = __builtin_amdgcn_mfma_f32_16x16x32_bf16(ah[cc], zfh[rc][ks], acc[rc][cc], 0, 0, 0);
          acc[rc][cc] = __builtin_amdgcn_mfma_f32_16x16x32_bf16(ah[cc], zfl[rc][ks], acc[rc][cc], 0, 0, 0);
          acc[rc][cc] = __builtin_amdgcn_mfma_f32_16x16x32_bf16(al[cc], zfh[rc][ks], acc[rc][cc], 0, 0, 0);
        }
    }
    {   // per-tile branch-free top-3 update
      int cbase = half * 4096 + t * 64 + wc * 32 + (lane >> 4) * 4;
      #pragma unroll
      for (int rc = 0; rc < 2; ++rc) {
        #pragma unroll
        for (int cc = 0; cc < 2; ++cc) {
          int cb2 = cbase + cc * 16;
          #pragma unroll
          for (int r = 0; r < 4; ++r) {
            float v = acc[rc][cc][r];
            int code = cb2 + r;
            bool gt1 = v > a1[rc];
            bool gt2 = v > a2[rc];
            float n1 = fmaxf(a1[rc], v);
            float n2 = __builtin_amdgcn_fmed3f(a1[rc], a2[rc], v);
            float n3 = fmaxf(a3[rc], fminf(a2[rc], v));
            int ni1 = gt1 ? code : i1[rc];
            int ni2 = gt1 ? i1[rc] : (gt2 ? code : i2[rc]);
            a1[rc] = n1; a2[rc] = n2; a3[rc] = n3; i1[rc] = ni1; i2[rc] = ni2;
          }
          acc[rc][cc] = (f32x4){0.f, 0.f, 0.f, 0.f};
        }
      }
    }
    __syncthreads();
  }
  #undef STAGE_E

  // merge lane-groups (lane^16, lane^32) holding the same rows
  #pragma unroll
  for (int rc = 0; rc < 2; ++rc) {
    #pragma unroll
    for (int off = 16; off < 64; off <<= 1) {
      float b1 = __shfl_xor(a1[rc], off, 64);
      float b2 = __shfl_xor(a2[rc], off, 64);
      float b3 = __shfl_xor(a3[rc], off, 64);
      int   j1 = __shfl_xor(i1[rc], off, 64);
      int   j2 = __shfl_xor(i2[rc], off, 64);
      mrg(a1[rc], i1[rc], a2[rc], i2[rc], a3[rc], b1, j1, b2, j2, b3);
    }
  }
  // cross-wave (wc) merge via LDS
  float* sa1 = (float*)smem;            // [2][128] each
  float* sa2 = sa1 + 256;
  float* sa3 = sa2 + 256;
  int*   si1 = (int*)(sa3 + 256);
  int*   si2 = si1 + 256;
  if ((lane >> 4) == 0) {
    #pragma unroll
    for (int rc = 0; rc < 2; ++rc) {
      int rl = wr * 32 + rc * 16 + lane;
      sa1[wc * 128 + rl] = a1[rc];
      sa2[wc * 128 + rl] = a2[rc];
      sa3[wc * 128 + rl] = a3[rc];
      si1[wc * 128 + rl] = i1[rc];
      si2[wc * 128 + rl] = i2[rc];
    }
  }
  __syncthreads();
  if (tid < 128) {
    float g1 = sa1[tid], g2 = sa2[tid], g3 = sa3[tid];
    int gi1 = si1[tid], gi2 = si2[tid];
    mrg(g1, gi1, g2, gi2, g3,
        sa1[128 + tid], si1[128 + tid],
        sa2[128 + tid], si2[128 + tid], sa3[128 + tid]);
    int n = rb + tid;
    pa1[half * N_TOT + n] = g1;
    pa2[half * N_TOT + n] = g2;
    pa3[half * N_TOT + n] = g3;
    pi1[half * N_TOT + n] = gi1;
    pi2[half * N_TOT + n] = gi2;
  }
}

// ---------- merge halves; emit idx, i2, and confirm/rescan lists ----------
__global__ __launch_bounds__(256) void k_merge(const float* __restrict__ pa1,
                                               const float* __restrict__ pa2,
                                               const float* __restrict__ pa3,
                                               const int* __restrict__ pi1,
                                               const int* __restrict__ pi2,
                                               int* __restrict__ idx,
                                               int* __restrict__ i2g,
                                               int* __restrict__ list2,
                                               int* __restrict__ listR,
                                               int* __restrict__ cnt,
                                               u64* __restrict__ rowbest) {
  int n = blockIdx.x * 256 + threadIdx.x;
  float g1 = pa1[n], g2 = pa2[n], g3 = pa3[n];
  int gi1 = pi1[n], gi2 = pi2[n];
  mrg(g1, gi1, g2, gi2, g3,
      pa1[N_TOT + n], pi1[N_TOT + n], pa2[N_TOT + n], pi2[N_TOT + n], pa3[N_TOT + n]);
  idx[n] = gi1;
  i2g[n] = gi2;
  if (g1 - g2 < TAU_A) {
    if (g1 - g3 >= W_CERT) { int p = atomicAdd(&cnt[0], 1); list2[p] = n; }
    else {
      int p = atomicAdd(&cnt[1], 1); listR[p] = n;
      rowbest[n] = 0xFFFFFFFFFFFFFFFFull;
    }
  }
}

// ---------- fused fixup: blocks 0..255 confirm-2, blocks 256..1279 rescan ----------
__global__ __launch_bounds__(256) void k_fix(const float* __restrict__ z,
                                             const float* __restrict__ emb,
                                             const float* __restrict__ szt,
                                             int* __restrict__ idx,
                                             const int* __restrict__ i2g,
                                             const int* __restrict__ list2,
                                             const int* __restrict__ listR,
                                             const int* __restrict__ cnt,
                                             u64* __restrict__ rowbest) {
  __shared__ float zrow[DIM];
  const int tid = threadIdx.x;
  const int lane = tid & 63, w = tid >> 6;
  if (blockIdx.x < 256) {
    // wave-parallel exact D over {i1, i2}
    const int nc = cnt[0];
    for (int q = blockIdx.x * 4 + w; q < nc; q += 1024) {
      int n = list2[q];
      int b = n >> 11, l = n & (LSEQ - 1);
      int c0 = idx[n], c1 = i2g[n];
      const float* zp = z + (size_t)b * DIM * LSEQ + l;
      float4 e0 = ((const float4*)emb)[(size_t)c0 * 64 + lane];
      float4 e1 = ((const float4*)emb)[(size_t)c1 * 64 + lane];
      float z0 = zp[(size_t)(4 * lane + 0) * LSEQ];
      float z1 = zp[(size_t)(4 * lane + 1) * LSEQ];
      float z2 = zp[(size_t)(4 * lane + 2) * LSEQ];
      float z3 = zp[(size_t)(4 * lane + 3) * LSEQ];
      double d0 = 0.0, d1 = 0.0;
      d0 = fma((double)e0.x, (double)z0, d0); d1 = fma((double)e1.x, (double)z0, d1);
      d0 = fma((double)e0.y, (double)z1, d0); d1 = fma((double)e1.y, (double)z1, d1);
      d0 = fma((double)e0.z, (double)z2, d0); d1 = fma((double)e1.z, (double)z2, d1);
      d0 = fma((double)e0.w, (double)z3, d0); d1 = fma((double)e1.w, (double)z3, d1);
      #pragma unroll
      for (int off = 32; off; off >>= 1) {
        d0 += __shfl_xor(d0, off, 64);
        d1 += __shfl_xor(d1, off, 64);
      }
      if (lane == 0) {
        float szv = szt[n];
        float D0 = __fsub_rn(szv, __fmul_rn(2.f, (float)d0));
        float D1 = __fsub_rn(szv, __fmul_rn(2.f, (float)d1));
        idx[n] = (D1 < D0 || (D1 == D0 && c1 < c0)) ? c1 : c0;
      }
    }
  } else {
    // rare-row rescan: wave-per-code-chunk, lane-parallel d, ILP-4 code batch
    const int nr = cnt[1];
    const int nitems = nr * 8;
    for (int item = blockIdx.x - 256; item < nitems; item += 1024) {
      int q = item >> 3, ck = item & 7;
      int n = listR[q];
      int b = n >> 11, l = n & (LSEQ - 1);
      zrow[tid] = z[(size_t)b * DIM * LSEQ + (size_t)tid * LSEQ + l];
      __syncthreads();
      float szv = szt[n];
      float zr0 = zrow[lane * 4 + 0], zr1 = zrow[lane * 4 + 1];
      float zr2 = zrow[lane * 4 + 2], zr3 = zrow[lane * 4 + 3];
      float bD = FLT_MAX; int bK = INT_MAX;
      int code0 = ck * 1024 + w * 256;
      for (int c4 = 0; c4 < 64; ++c4) {
        int codeb = code0 + c4 * 4;
        double dt[4];
        #pragma unroll
        for (int u = 0; u < 4; ++u) {
          float4 e4 = ((const float4*)emb)[(size_t)(codeb + u) * 64 + lane];
          double dot = 0.0;
          dot = fma((double)e4.x, (double)zr0, dot);
          dot = fma((double)e4.y, (double)zr1, dot);
          dot = fma((double)e4.z, (double)zr2, dot);
          dot = fma((double)e4.w, (double)zr3, dot);
          dt[u] = dot;
        }
        #pragma unroll
        for (int off = 32; off; off >>= 1) {
          #pragma unroll
          for (int u = 0; u < 4; ++u) dt[u] += __shfl_xor(dt[u], off, 64);
        }
        #pragma unroll
        for (int u = 0; u < 4; ++u) {
          int code = codeb + u;
          float D = __fsub_rn(szv, __fmul_rn(2.f, (float)dt[u]));
          if (D < bD || (D == bD && code < bK)) { bD = D; bK = code; }
        }
      }
      if (lane == 0) {
        u64 key = ((u64)__float_as_uint(bD) << 32) | (u32)bK;
        atomicMin(rowbest + n, key);
      }
      __syncthreads();
    }
  }
}

// ---------- resolve rescan winners into idx ----------
__global__ __launch_bounds__(256) void k_resolve(int* __restrict__ idx,
                                                 const u64* __restrict__ rowbest,
                                                 const int* __restrict__ listR,
                                                 const int* __restrict__ cnt) {
  const int nr = cnt[1];
  for (int q = blockIdx.x * 256 + threadIdx.x; q < nr; q += gridDim.x * 256) {
    int n = listR[q];
    u64 rbv = rowbest[n];
    if (rbv != 0xFFFFFFFFFFFFFFFFull) idx[n] = (int)(rbv & 0xFFFFFFFFu);
  }
}

// ---------- gather + loss partials ----------
__global__ __launch_bounds__(256) void k_gather(const float* __restrict__ z,
                                                const float* __restrict__ emb,
                                                const int* __restrict__ idx,
                                                float* __restrict__ zq_out,
                                                float* __restrict__ idxf_out,
                                                float* __restrict__ partial) {
  __shared__ int il[64];
  __shared__ float red[4];
  const int tid = threadIdx.x;
  const int n0 = blockIdx.x * 64;
  const int b = n0 >> 11, l0 = n0 & (LSEQ - 1);
  if (tid < 64) {
    int v = idx[n0 + tid];
    il[tid] = v;
    idxf_out[n0 + tid] = (float)v;
  }
  __syncthreads();
  const int dgrp = tid >> 6;
  const int lo   = tid & 63;
  const size_t zb = (size_t)b * DIM * LSEQ + l0 + lo;
  const int myidx = il[lo];
  float acc = 0.f;
  #pragma unroll 4
  for (int dd = 0; dd < 64; ++dd) {
    int d = dgrp + dd * 4;
    float e  = emb[(size_t)myidx * DIM + d];
    float zv = z[zb + (size_t)d * LSEQ];
    zq_out[zb + (size_t)d * LSEQ] = e;
    float df = e - zv;
    acc = fmaf(df, df, acc);
  }
  #pragma unroll
  for (int off = 1; off < 64; off <<= 1) acc += __shfl_xor(acc, off, 64);
  if ((tid & 63) == 0) red[tid >> 6] = acc;
  __syncthreads();
  if (tid == 0) partial[blockIdx.x] = red[0] + red[1] + red[2] + red[3];
}

__global__ __launch_bounds__(256) void k_loss(const float* __restrict__ partial,
                                              float* __restrict__ out_loss) {
  const int tid = threadIdx.x;
  double a = (double)partial[tid];
  #pragma unroll
  for (int off = 1; off < 64; off <<= 1) a += __shfl_xor(a, off, 64);
  __shared__ double r[4];
  if ((tid & 63) == 0) r[tid >> 6] = a;
  __syncthreads();
  if (tid == 0) {
    double s = r[0] + r[1] + r[2] + r[3];
    out_loss[0] = (float)(1.25 * s / (double)((size_t)N_TOT * DIM));
  }
}

extern "C" void kernel_launch(void* const* d_in, const int* in_sizes, int n_in,
                              void* d_out, int out_size, void* d_ws, size_t ws_size,
                              hipStream_t stream) {
  const float* z   = (const float*)d_in[0];
  const float* emb = (const float*)d_in[1];
  float* out = (float*)d_out;
  char* ws = (char*)d_ws;

  u16*   zhi  = (u16*)(ws + WS_ZT_HI);
  u16*   zlo  = (u16*)(ws + WS_ZT_LO);
  u16*   ehi  = (u16*)(ws + WS_E_HI);
  u16*   elo  = (u16*)(ws + WS_E_LO);
  float* sz   = (float*)(ws + WS_SZ);
  int*   idx  = (int*)(ws + WS_IDX);
  int*   i2g  = (int*)(ws + WS_I2G);
  int*   list2= (int*)(ws + WS_LIST2);
  int*   cnt  = (int*)(ws + WS_CNT);
  float* part = (float*)(ws + WS_PART);
  float* pa1  = (float*)(ws + WS_PA1);
  float* pa2  = (float*)(ws + WS_PA2);
  int*   pi1  = (int*)(ws + WS_PI1);
  float* pa3  = (float*)(ws + WS_PA3);
  int*   pi2  = (int*)(ws + WS_PI2);
  int*   listR= (int*)(ws + WS_LISTR);
  u64*   rb   = (u64*)(ws + WS_RB);

  float* zq_out   = out;
  float* loss_out = out + (size_t)N_TOT * DIM;
  float* idxf_out = out + (size_t)N_TOT * DIM + 1;

  k_prep   <<<128,  256, 0, stream>>>(z, zhi, zlo, sz);
  k_split_e<<<2048, 256, 0, stream>>>(emb, ehi, elo, cnt);
  k_mfma   <<<256,  512, 131072, stream>>>(zhi, zlo, ehi, elo, pa1, pa2, pa3, pi1, pi2);
  k_merge  <<<64,   256, 0, stream>>>(pa1, pa2, pa3, pi1, pi2, idx, i2g, list2, listR, cnt, rb);
  k_fix    <<<1280, 256, 0, stream>>>(z, emb, sz, idx, i2g, list2, listR, cnt, rb);
  k_resolve<<<8,    256, 0, stream>>>(idx, rb, listR, cnt);
  k_gather <<<256,  256, 0, stream>>>(z, emb, idx, zq_out, idxf_out, part);
  k_loss   <<<1,    256, 0, stream>>>(part, loss_out);
}

// Round 17
// 308.336 us; speedup vs baseline: 1.7426x; 1.0030x over previous
//
#include <hip/hip_runtime.h>
#include <hip/hip_bf16.h>
#include <math.h>
#include <float.h>
#include <limits.h>

#define N_TOT   16384
#define DIM     256
#define KCB     8192
#define LSEQ    2048
#define TAU_A   1.8e-5f
#define W_CERT  1.7e-5f

typedef unsigned short u16;
typedef unsigned int   u32;
typedef unsigned long long u64;
typedef __attribute__((ext_vector_type(8))) short bf16x8;
typedef __attribute__((ext_vector_type(4))) float f32x4;

// ws layout (bytes)
#define WS_ZT_HI 0u
#define WS_ZT_LO 8388608u
#define WS_E_HI  16777216u
#define WS_E_LO  20971520u
#define WS_SZ    25165824u
#define WS_IDX   25231360u
#define WS_I2G   25296896u
#define WS_LIST2 25362432u
#define WS_CNT   25427968u
#define WS_PART  25428992u
#define WS_PA1   25430016u
#define WS_PA2   25561088u
#define WS_PI1   25692160u
#define WS_PA3   25823232u
#define WS_PI2   25954304u
#define WS_LISTR 26085376u
#define WS_RB    26150912u

__device__ __forceinline__ u16 f2bf_bits(float x) {
  __hip_bfloat16 h = __float2bfloat16(x);
  return *reinterpret_cast<u16*>(&h);
}
__device__ __forceinline__ float bfbits2f(u16 b) {
  __hip_bfloat16 h = *reinterpret_cast<__hip_bfloat16*>(&b);
  return __bfloat162float(h);
}

__device__ __forceinline__ void gl_lds16(const void* g, void* l) {
  __builtin_amdgcn_global_load_lds(
      (const __attribute__((address_space(1))) u32*)g,
      (__attribute__((address_space(3))) u32*)l, 16, 0, 0);
}

// merge two sorted (desc, idx-asc-on-tie) triples; slot3 value-only
__device__ __forceinline__ void mrg(float& a1, int& i1, float& a2, int& i2, float& a3,
                                    float b1, int j1, float b2, int j2, float b3) {
  bool bfirst = (b1 > a1) || (b1 == a1 && j1 < i1);
  float c1 = bfirst ? b1 : a1;
  int   k1 = bfirst ? j1 : i1;
  float wh2 = bfirst ? b2 : a2, wh3 = bfirst ? b3 : a3;
  int   wk2 = bfirst ? j2 : i2;
  float lh1 = bfirst ? a1 : b1, lh2 = bfirst ? a2 : b2;
  int   lk1 = bfirst ? i1 : j1;
  bool l2 = (lh1 > wh2) || (lh1 == wh2 && lk1 < wk2);
  float c2, c3; int k2;
  if (l2) { c2 = lh1; k2 = lk1; c3 = fmaxf(wh2, lh2); }
  else    { c2 = wh2; k2 = wk2; c3 = fmaxf(wh3, lh1); }
  a1 = c1; i1 = k1; a2 = c2; i2 = k2; a3 = c3;
}

// ---------- fused: split z -> bf16 hi/lo AND np-replica row norms ----------
__global__ __launch_bounds__(256) void k_prep(const float* __restrict__ z,
                                              u16* __restrict__ zhi,
                                              u16* __restrict__ zlo,
                                              float* __restrict__ sz) {
  int g = blockIdx.x * 256 + threadIdx.x;   // 32768 = 16384 rows x 2 halves
  int n = g >> 1, half = g & 1;
  int b = n >> 11, l = n & (LSEQ - 1);
  const float* zp = z + (size_t)b * DIM * LSEQ + l;
  const int d0 = half * 128;
  u16* ph = zhi + (size_t)n * DIM + d0;
  u16* pl = zlo + (size_t)n * DIM + d0;
  float r[8];
  u32 hw[8], lw[8];
  #pragma unroll
  for (int i = 0; i < 128; i += 8) {
    #pragma unroll
    for (int j = 0; j < 8; ++j) {
      int dd = i + j;
      float v = zp[(size_t)(d0 + dd) * LSEQ];
      float sq = __fmul_rn(v, v);
      r[j] = (i == 0) ? sq : __fadd_rn(r[j], sq);
      u16 hb = f2bf_bits(v);
      u16 lb = f2bf_bits(v - bfbits2f(hb));
      int wi = (dd >> 1) & 7;
      if (dd & 1) { hw[wi] |= (u32)hb << 16; lw[wi] |= (u32)lb << 16; }
      else        { hw[wi]  = hb;            lw[wi]  = lb; }
    }
    if (i & 8) {
      int gb = i - 8;
      *(uint4*)(ph + gb)     = make_uint4(hw[0], hw[1], hw[2], hw[3]);
      *(uint4*)(ph + gb + 8) = make_uint4(hw[4], hw[5], hw[6], hw[7]);
      *(uint4*)(pl + gb)     = make_uint4(lw[0], lw[1], lw[2], lw[3]);
      *(uint4*)(pl + gb + 8) = make_uint4(lw[4], lw[5], lw[6], lw[7]);
    }
  }
  float hsum = __fadd_rn(__fadd_rn(__fadd_rn(r[0], r[1]), __fadd_rn(r[2], r[3])),
                         __fadd_rn(__fadd_rn(r[4], r[5]), __fadd_rn(r[6], r[7])));
  float other = __shfl_xor(hsum, 1, 64);
  if (half == 0) sz[n] = __fadd_rn(hsum, other);
}

// ---------- split emb [k][d] -> e_hi/e_lo bf16 (+ counters zero) ----------
__global__ __launch_bounds__(256) void k_split_e(const float* __restrict__ emb,
                                                 u16* __restrict__ ehi,
                                                 u16* __restrict__ elo,
                                                 int* __restrict__ cnt) {
  if (blockIdx.x == 0 && threadIdx.x == 0) { cnt[0] = 0; cnt[1] = 0; }
  int g = blockIdx.x * 256 + threadIdx.x;   // 2048 blocks, 4 floats each
  float4 v = ((const float4*)emb)[g];
  u16 h0 = f2bf_bits(v.x), h1 = f2bf_bits(v.y), h2 = f2bf_bits(v.z), h3 = f2bf_bits(v.w);
  u16 l0 = f2bf_bits(v.x - bfbits2f(h0));
  u16 l1 = f2bf_bits(v.y - bfbits2f(h1));
  u16 l2 = f2bf_bits(v.z - bfbits2f(h2));
  u16 l3 = f2bf_bits(v.w - bfbits2f(h3));
  ((uint2*)ehi)[g] = make_uint2((u32)h0 | ((u32)h1 << 16), (u32)h2 | ((u32)h3 << 16));
  ((uint2*)elo)[g] = make_uint2((u32)l0 | ((u32)l1 << 16), (u32)l2 | ((u32)l3 << 16));
}

// ---------- MFMA top-3 phase-1 (r14 geometry; top-3 moved past the barrier) ----------
__global__ __launch_bounds__(512) void k_mfma(const u16* __restrict__ zhi_g,
                                              const u16* __restrict__ zlo_g,
                                              const u16* __restrict__ ehi_g,
                                              const u16* __restrict__ elo_g,
                                              float* __restrict__ pa1,
                                              float* __restrict__ pa2,
                                              float* __restrict__ pa3,
                                              int* __restrict__ pi1,
                                              int* __restrict__ pi2) {
  extern __shared__ char smem[];
  const int tid = threadIdx.x;
  const int lane = tid & 63, w = tid >> 6;
  const int wr = w >> 1, wc = w & 1;          // 4 row-waves x 2 col-waves
  const int bid = blockIdx.x;
  const int half = bid & 1;
  const int rb = (bid >> 1) * 128;
  const size_t zrow0 = (size_t)rb * 512;
  const size_t ecol0 = (size_t)half * 4096 * 512;
  const int srcoff = ((lane >> 3) << 9) + ((((lane & 7) ^ ((lane >> 3) & 7))) << 4);
  const int sarr = w & 1;                     // staging role: 0=hi, 1=lo
  const int sgrp = w >> 1;                    // 0..3

  // z fragments -> registers (32 x bf16x8 per thread)
  bf16x8 zfh[2][8], zfl[2][8];
  {
    const char* zh = (const char*)zhi_g + zrow0;
    const char* zl = (const char*)zlo_g + zrow0;
    #pragma unroll
    for (int rt = 0; rt < 2; ++rt) {
      int rowb = (wr * 32 + rt * 16 + (lane & 15)) * 512 + ((lane >> 4) << 4);
      #pragma unroll
      for (int ks = 0; ks < 8; ++ks) {
        zfh[rt][ks] = *(const bf16x8*)(zh + rowb + ks * 64);
        zfl[rt][ks] = *(const bf16x8*)(zl + rowb + ks * 64);
      }
    }
  }

  // e staging: tile T (64 codes x 256 d, hi+lo = 64KB) into dbuf half (T&1)
  #define STAGE_E(T) {                                                      \
    const char* esrc_ = ((sarr == 0) ? (const char*)ehi_g                   \
                                     : (const char*)elo_g) + ecol0          \
                        + (size_t)(T) * 32768;                              \
    char* ebuf_ = smem + (((T) & 1) << 16) + sarr * 32768;                  \
    _Pragma("unroll")                                                       \
    for (int dq_ = 0; dq_ < 4; ++dq_) {                                     \
      _Pragma("unroll")                                                     \
      for (int j_ = 0; j_ < 2; ++j_) {                                      \
        int c_ = sgrp * 2 + j_;                                             \
        gl_lds16(esrc_ + c_ * 4096 + dq_ * 128 + srcoff,                    \
                 ebuf_ + dq_ * 8192 + c_ * 1024);                           \
      }                                                                     \
    }                                                                       \
  }

  STAGE_E(0);

  f32x4 acc[2][2];
  #pragma unroll
  for (int rc = 0; rc < 2; ++rc)
    #pragma unroll
    for (int cc = 0; cc < 2; ++cc) acc[rc][cc] = (f32x4){0.f, 0.f, 0.f, 0.f};

  float a1[2], a2[2], a3[2]; int i1[2], i2[2];
  #pragma unroll
  for (int rc = 0; rc < 2; ++rc) {
    a1[rc] = -FLT_MAX; a2[rc] = -FLT_MAX; a3[rc] = -FLT_MAX; i1[rc] = 0; i2[rc] = 0;
  }

  int cbyte[2];
  #pragma unroll
  for (int cc = 0; cc < 2; ++cc) cbyte[cc] = (wc * 32 + cc * 16 + (lane & 15)) * 128;

  __syncthreads();

  for (int t = 0; t < 64; ++t) {
    if (t + 1 < 64) STAGE_E(t + 1);
    const char* bb = smem + ((t & 1) << 16);
    #pragma unroll
    for (int ks = 0; ks < 8; ++ks) {
      const int dq = ks >> 1, kc = ks & 1;
      const char* beh = bb + dq * 8192;
      const char* bel = bb + 32768 + dq * 8192;
      int coff = ((kc * 4 + (lane >> 4)) ^ (lane & 7)) << 4;
      bf16x8 ah[2], al[2];
      #pragma unroll
      for (int cc = 0; cc < 2; ++cc) {
        ah[cc] = *(const bf16x8*)(beh + cbyte[cc] + coff);
        al[cc] = *(const bf16x8*)(bel + cbyte[cc] + coff);
      }
      #pragma unroll
      for (int rc = 0; rc < 2; ++rc)
        #pragma unroll
        for (int cc = 0; cc < 2; ++cc) {
          acc[rc][cc] = __builtin_amdgcn_mfma_f32_16x16x32_bf16(ah[cc], zfh[rc][ks], acc[rc][cc], 0, 0, 0);
          acc[rc][cc] = __builtin_amdgcn_mfma_f32_16x16x32_bf16(ah[cc], zfl[rc][ks], acc[rc][cc], 0, 0, 0);
          acc[rc][cc] = __builtin_amdgcn_mfma_f32_16x16x32_bf16(al[cc], zfh[rc][ks], acc[rc][cc], 0, 0, 0);
        }
    }
    // barrier first: LDS buffer protocol unchanged (staged writes visible,
    // reads of buf t done). Top-3 (register-only) runs after, overlapping the
    // next tile's staging/ds_reads instead of extending the barrier path.
    __syncthreads();
    {   // per-tile branch-free top-3 update (register-only)
      int cbase = half * 4096 + t * 64 + wc * 32 + (lane >> 4) * 4;
      #pragma unroll
      for (int rc = 0; rc < 2; ++rc) {
        #pragma unroll
        for (int cc = 0; cc < 2; ++cc) {
          int cb2 = cbase + cc * 16;
          #pragma unroll
          for (int r = 0; r < 4; ++r) {
            float v = acc[rc][cc][r];
            int code = cb2 + r;
            bool gt1 = v > a1[rc];
            bool gt2 = v > a2[rc];
            float n1 = fmaxf(a1[rc], v);
            float n2 = __builtin_amdgcn_fmed3f(a1[rc], a2[rc], v);
            float n3 = fmaxf(a3[rc], fminf(a2[rc], v));
            int ni1 = gt1 ? code : i1[rc];
            int ni2 = gt1 ? i1[rc] : (gt2 ? code : i2[rc]);
            a1[rc] = n1; a2[rc] = n2; a3[rc] = n3; i1[rc] = ni1; i2[rc] = ni2;
          }
          acc[rc][cc] = (f32x4){0.f, 0.f, 0.f, 0.f};
        }
      }
    }
  }
  #undef STAGE_E

  // merge lane-groups (lane^16, lane^32) holding the same rows
  #pragma unroll
  for (int rc = 0; rc < 2; ++rc) {
    #pragma unroll
    for (int off = 16; off < 64; off <<= 1) {
      float b1 = __shfl_xor(a1[rc], off, 64);
      float b2 = __shfl_xor(a2[rc], off, 64);
      float b3 = __shfl_xor(a3[rc], off, 64);
      int   j1 = __shfl_xor(i1[rc], off, 64);
      int   j2 = __shfl_xor(i2[rc], off, 64);
      mrg(a1[rc], i1[rc], a2[rc], i2[rc], a3[rc], b1, j1, b2, j2, b3);
    }
  }
  // cross-wave (wc) merge via LDS
  float* sa1 = (float*)smem;            // [2][128] each
  float* sa2 = sa1 + 256;
  float* sa3 = sa2 + 256;
  int*   si1 = (int*)(sa3 + 256);
  int*   si2 = si1 + 256;
  __syncthreads();
  if ((lane >> 4) == 0) {
    #pragma unroll
    for (int rc = 0; rc < 2; ++rc) {
      int rl = wr * 32 + rc * 16 + lane;
      sa1[wc * 128 + rl] = a1[rc];
      sa2[wc * 128 + rl] = a2[rc];
      sa3[wc * 128 + rl] = a3[rc];
      si1[wc * 128 + rl] = i1[rc];
      si2[wc * 128 + rl] = i2[rc];
    }
  }
  __syncthreads();
  if (tid < 128) {
    float g1 = sa1[tid], g2 = sa2[tid], g3 = sa3[tid];
    int gi1 = si1[tid], gi2 = si2[tid];
    mrg(g1, gi1, g2, gi2, g3,
        sa1[128 + tid], si1[128 + tid],
        sa2[128 + tid], si2[128 + tid], sa3[128 + tid]);
    int n = rb + tid;
    pa1[half * N_TOT + n] = g1;
    pa2[half * N_TOT + n] = g2;
    pa3[half * N_TOT + n] = g3;
    pi1[half * N_TOT + n] = gi1;
    pi2[half * N_TOT + n] = gi2;
  }
}

// ---------- merge halves; emit idx, i2, lists; init rowbest for ALL rows ----------
__global__ __launch_bounds__(256) void k_merge(const float* __restrict__ pa1,
                                               const float* __restrict__ pa2,
                                               const float* __restrict__ pa3,
                                               const int* __restrict__ pi1,
                                               const int* __restrict__ pi2,
                                               int* __restrict__ idx,
                                               int* __restrict__ i2g,
                                               int* __restrict__ list2,
                                               int* __restrict__ listR,
                                               int* __restrict__ cnt,
                                               u64* __restrict__ rowbest) {
  int n = blockIdx.x * 256 + threadIdx.x;
  float g1 = pa1[n], g2 = pa2[n], g3 = pa3[n];
  int gi1 = pi1[n], gi2 = pi2[n];
  mrg(g1, gi1, g2, gi2, g3,
      pa1[N_TOT + n], pi1[N_TOT + n], pa2[N_TOT + n], pi2[N_TOT + n], pa3[N_TOT + n]);
  idx[n] = gi1;
  i2g[n] = gi2;
  rowbest[n] = 0xFFFFFFFFFFFFFFFFull;
  if (g1 - g2 < TAU_A) {
    if (g1 - g3 >= W_CERT) { int p = atomicAdd(&cnt[0], 1); list2[p] = n; }
    else                   { int p = atomicAdd(&cnt[1], 1); listR[p] = n; }
  }
}

// ---------- fused fixup: blocks 0..255 confirm-2, blocks 256..1279 rescan ----------
__global__ __launch_bounds__(256) void k_fix(const float* __restrict__ z,
                                             const float* __restrict__ emb,
                                             const float* __restrict__ szt,
                                             int* __restrict__ idx,
                                             const int* __restrict__ i2g,
                                             const int* __restrict__ list2,
                                             const int* __restrict__ listR,
                                             const int* __restrict__ cnt,
                                             u64* __restrict__ rowbest) {
  __shared__ float zrow[DIM];
  const int tid = threadIdx.x;
  const int lane = tid & 63, w = tid >> 6;
  if (blockIdx.x < 256) {
    // wave-parallel exact D over {i1, i2}
    const int nc = cnt[0];
    for (int q = blockIdx.x * 4 + w; q < nc; q += 1024) {
      int n = list2[q];
      int b = n >> 11, l = n & (LSEQ - 1);
      int c0 = idx[n], c1 = i2g[n];
      const float* zp = z + (size_t)b * DIM * LSEQ + l;
      float4 e0 = ((const float4*)emb)[(size_t)c0 * 64 + lane];
      float4 e1 = ((const float4*)emb)[(size_t)c1 * 64 + lane];
      float z0 = zp[(size_t)(4 * lane + 0) * LSEQ];
      float z1 = zp[(size_t)(4 * lane + 1) * LSEQ];
      float z2 = zp[(size_t)(4 * lane + 2) * LSEQ];
      float z3 = zp[(size_t)(4 * lane + 3) * LSEQ];
      double d0 = 0.0, d1 = 0.0;
      d0 = fma((double)e0.x, (double)z0, d0); d1 = fma((double)e1.x, (double)z0, d1);
      d0 = fma((double)e0.y, (double)z1, d0); d1 = fma((double)e1.y, (double)z1, d1);
      d0 = fma((double)e0.z, (double)z2, d0); d1 = fma((double)e1.z, (double)z2, d1);
      d0 = fma((double)e0.w, (double)z3, d0); d1 = fma((double)e1.w, (double)z3, d1);
      #pragma unroll
      for (int off = 32; off; off >>= 1) {
        d0 += __shfl_xor(d0, off, 64);
        d1 += __shfl_xor(d1, off, 64);
      }
      if (lane == 0) {
        float szv = szt[n];
        float D0 = __fsub_rn(szv, __fmul_rn(2.f, (float)d0));
        float D1 = __fsub_rn(szv, __fmul_rn(2.f, (float)d1));
        idx[n] = (D1 < D0 || (D1 == D0 && c1 < c0)) ? c1 : c0;
      }
    }
  } else {
    // rare-row rescan: wave-per-code-chunk, lane-parallel d, ILP-4 code batch
    const int nr = cnt[1];
    const int nitems = nr * 8;
    for (int item = blockIdx.x - 256; item < nitems; item += 1024) {
      int q = item >> 3, ck = item & 7;
      int n = listR[q];
      int b = n >> 11, l = n & (LSEQ - 1);
      zrow[tid] = z[(size_t)b * DIM * LSEQ + (size_t)tid * LSEQ + l];
      __syncthreads();
      float szv = szt[n];
      float zr0 = zrow[lane * 4 + 0], zr1 = zrow[lane * 4 + 1];
      float zr2 = zrow[lane * 4 + 2], zr3 = zrow[lane * 4 + 3];
      float bD = FLT_MAX; int bK = INT_MAX;
      int code0 = ck * 1024 + w * 256;
      for (int c4 = 0; c4 < 64; ++c4) {
        int codeb = code0 + c4 * 4;
        double dt[4];
        #pragma unroll
        for (int u = 0; u < 4; ++u) {
          float4 e4 = ((const float4*)emb)[(size_t)(codeb + u) * 64 + lane];
          double dot = 0.0;
          dot = fma((double)e4.x, (double)zr0, dot);
          dot = fma((double)e4.y, (double)zr1, dot);
          dot = fma((double)e4.z, (double)zr2, dot);
          dot = fma((double)e4.w, (double)zr3, dot);
          dt[u] = dot;
        }
        #pragma unroll
        for (int off = 32; off; off >>= 1) {
          #pragma unroll
          for (int u = 0; u < 4; ++u) dt[u] += __shfl_xor(dt[u], off, 64);
        }
        #pragma unroll
        for (int u = 0; u < 4; ++u) {
          int code = codeb + u;
          float D = __fsub_rn(szv, __fmul_rn(2.f, (float)dt[u]));
          if (D < bD || (D == bD && code < bK)) { bD = D; bK = code; }
        }
      }
      if (lane == 0) {
        u64 key = ((u64)__float_as_uint(bD) << 32) | (u32)bK;
        atomicMin(rowbest + n, key);
      }
      __syncthreads();
    }
  }
}

// ---------- gather + loss partials (inline rowbest resolution) ----------
__global__ __launch_bounds__(256) void k_gather(const float* __restrict__ z,
                                                const float* __restrict__ emb,
                                                const int* __restrict__ idx,
                                                const u64* __restrict__ rowbest,
                                                float* __restrict__ zq_out,
                                                float* __restrict__ idxf_out,
                                                float* __restrict__ partial) {
  __shared__ int il[64];
  __shared__ float red[4];
  const int tid = threadIdx.x;
  const int n0 = blockIdx.x * 64;
  const int b = n0 >> 11, l0 = n0 & (LSEQ - 1);
  if (tid < 64) {
    int n = n0 + tid;
    int v = idx[n];
    u64 rbv = rowbest[n];
    if (rbv != 0xFFFFFFFFFFFFFFFFull) v = (int)(rbv & 0xFFFFFFFFu);
    il[tid] = v;
    idxf_out[n] = (float)v;
  }
  __syncthreads();
  const int dgrp = tid >> 6;
  const int lo   = tid & 63;
  const size_t zb = (size_t)b * DIM * LSEQ + l0 + lo;
  const int myidx = il[lo];
  float acc = 0.f;
  #pragma unroll 4
  for (int dd = 0; dd < 64; ++dd) {
    int d = dgrp + dd * 4;
    float e  = emb[(size_t)myidx * DIM + d];
    float zv = z[zb + (size_t)d * LSEQ];
    zq_out[zb + (size_t)d * LSEQ] = e;
    float df = e - zv;
    acc = fmaf(df, df, acc);
  }
  #pragma unroll
  for (int off = 1; off < 64; off <<= 1) acc += __shfl_xor(acc, off, 64);
  if ((tid & 63) == 0) red[tid >> 6] = acc;
  __syncthreads();
  if (tid == 0) partial[blockIdx.x] = red[0] + red[1] + red[2] + red[3];
}

__global__ __launch_bounds__(256) void k_loss(const float* __restrict__ partial,
                                              float* __restrict__ out_loss) {
  const int tid = threadIdx.x;
  double a = (double)partial[tid];
  #pragma unroll
  for (int off = 1; off < 64; off <<= 1) a += __shfl_xor(a, off, 64);
  __shared__ double r[4];
  if ((tid & 63) == 0) r[tid >> 6] = a;
  __syncthreads();
  if (tid == 0) {
    double s = r[0] + r[1] + r[2] + r[3];
    out_loss[0] = (float)(1.25 * s / (double)((size_t)N_TOT * DIM));
  }
}

extern "C" void kernel_launch(void* const* d_in, const int* in_sizes, int n_in,
                              void* d_out, int out_size, void* d_ws, size_t ws_size,
                              hipStream_t stream) {
  const float* z   = (const float*)d_in[0];
  const float* emb = (const float*)d_in[1];
  float* out = (float*)d_out;
  char* ws = (char*)d_ws;

  u16*   zhi  = (u16*)(ws + WS_ZT_HI);
  u16*   zlo  = (u16*)(ws + WS_ZT_LO);
  u16*   ehi  = (u16*)(ws + WS_E_HI);
  u16*   elo  = (u16*)(ws + WS_E_LO);
  float* sz   = (float*)(ws + WS_SZ);
  int*   idx  = (int*)(ws + WS_IDX);
  int*   i2g  = (int*)(ws + WS_I2G);
  int*   list2= (int*)(ws + WS_LIST2);
  int*   cnt  = (int*)(ws + WS_CNT);
  float* part = (float*)(ws + WS_PART);
  float* pa1  = (float*)(ws + WS_PA1);
  float* pa2  = (float*)(ws + WS_PA2);
  int*   pi1  = (int*)(ws + WS_PI1);
  float* pa3  = (float*)(ws + WS_PA3);
  int*   pi2  = (int*)(ws + WS_PI2);
  int*   listR= (int*)(ws + WS_LISTR);
  u64*   rb   = (u64*)(ws + WS_RB);

  float* zq_out   = out;
  float* loss_out = out + (size_t)N_TOT * DIM;
  float* idxf_out = out + (size_t)N_TOT * DIM + 1;

  k_prep   <<<128,  256, 0, stream>>>(z, zhi, zlo, sz);
  k_split_e<<<2048, 256, 0, stream>>>(emb, ehi, elo, cnt);
  k_mfma   <<<256,  512, 131072, stream>>>(zhi, zlo, ehi, elo, pa1, pa2, pa3, pi1, pi2);
  k_merge  <<<64,   256, 0, stream>>>(pa1, pa2, pa3, pi1, pi2, idx, i2g, list2, listR, cnt, rb);
  k_fix    <<<1280, 256, 0, stream>>>(z, emb, sz, idx, i2g, list2, listR, cnt, rb);
  k_gather <<<256,  256, 0, stream>>>(z, emb, idx, rb, zq_out, idxf_out, part);
  k_loss   <<<1,    256, 0, stream>>>(part, loss_out);
}